// Round 2
// baseline (221.359 us; speedup 1.0000x reference)
//
#include <hip/hip_runtime.h>
#include <hip/hip_bf16.h>

// GAT layer: N=4096, F_IN=128, F_OUT=64, HEADS=4.
// R2: K-split gat_main across 4 blocks (grid 256x4 = 1024 blocks, 4 blocks/CU,
//     32 waves/CU) writing UNNORMALIZED partials via global atomics; finalize
//     kernel applies softmax denominator + diagonal self-edge + head-sum.
// Kernels: zero_f4 -> gat_prep -> gat_main -> gat_fin.

#define NN 4096
#define FIN 128
#define FOUT 64
#define NH 4

typedef __attribute__((ext_vector_type(8))) short bf16x8;
typedef __attribute__((ext_vector_type(4))) float f32x4;

__device__ __forceinline__ unsigned short f32_bf16(float f) {
    unsigned u = __builtin_bit_cast(unsigned, f);
    u += 0x7fffu + ((u >> 16) & 1u);          // round-to-nearest-even
    return (unsigned short)(u >> 16);
}

// ---------------- Kernel 0: zero the accumulation workspace ----------------
__global__ __launch_bounds__(256) void zero_f4(float4* __restrict__ p, int n4) {
    int i = blockIdx.x * 256 + threadIdx.x;
    if (i < n4) p[i] = make_float4(0.f, 0.f, 0.f, 0.f);
}

// ---------------- Kernel 1: prep ----------------
// H = X@W[h]^T + b (fp32). Outputs: bf16 H^T [h][o][n] (for MFMA B-operand),
// fp32 Hrow [h][n][o] (for diagonal term in finalize), s[h][n], d[h][n].
__global__ __launch_bounds__(256) void gat_prep(
    const float* __restrict__ X, const float* __restrict__ W,
    const float* __restrict__ b, const float* __restrict__ att,
    unsigned short* __restrict__ HbfT, float* __restrict__ Hrow,
    float* __restrict__ s_out, float* __restrict__ d_out)
{
    const int rb = blockIdx.x;           // 0..127
    const int h  = blockIdx.y;           // 0..3
    const int n0 = rb * 32;
    const int t  = threadIdx.x;          // 0..255

    __shared__ float Xl[32][132];        // 32 rows x 128 (pad)
    __shared__ float Wt[128][68];        // W[h]^T [f][o] (pad)

    for (int g = t; g < 32 * 32; g += 256) {
        int row = g >> 5, c4 = g & 31;
        float4 v = *(const float4*)&X[(size_t)(n0 + row) * FIN + c4 * 4];
        *(float4*)&Xl[row][c4 * 4] = v;
    }
    for (int g = t; g < 64 * 32; g += 256) {
        int o = g >> 5, c4 = g & 31;
        float4 v = *(const float4*)&W[((size_t)h * FOUT + o) * FIN + c4 * 4];
        Wt[c4 * 4 + 0][o] = v.x; Wt[c4 * 4 + 1][o] = v.y;
        Wt[c4 * 4 + 2][o] = v.z; Wt[c4 * 4 + 3][o] = v.w;
    }
    __syncthreads();

    const int rg = t >> 4;               // rows rg*2 .. rg*2+1
    const int og = t & 15;               // cols og*4 .. og*4+3
    float acc[2][4] = {};

    #pragma unroll 4
    for (int f4 = 0; f4 < 32; ++f4) {
        float xv[2][4], wv[4][4];
        #pragma unroll
        for (int i = 0; i < 2; ++i) {
            float4 tmp = *(const float4*)&Xl[rg * 2 + i][f4 * 4];
            xv[i][0] = tmp.x; xv[i][1] = tmp.y; xv[i][2] = tmp.z; xv[i][3] = tmp.w;
        }
        #pragma unroll
        for (int k = 0; k < 4; ++k) {
            float4 tmp = *(const float4*)&Wt[f4 * 4 + k][og * 4];
            wv[k][0] = tmp.x; wv[k][1] = tmp.y; wv[k][2] = tmp.z; wv[k][3] = tmp.w;
        }
        #pragma unroll
        for (int i = 0; i < 2; ++i)
            #pragma unroll
            for (int k = 0; k < 4; ++k)
                #pragma unroll
                for (int jj = 0; jj < 4; ++jj)
                    acc[i][jj] = fmaf(xv[i][k], wv[k][jj], acc[i][jj]);
    }

    float bb[4], as_[4], ad_[4];
    #pragma unroll
    for (int jj = 0; jj < 4; ++jj) {
        bb[jj]  = b[h * FOUT + og * 4 + jj];
        as_[jj] = att[h * 2 * FOUT + og * 4 + jj];
        ad_[jj] = att[h * 2 * FOUT + FOUT + og * 4 + jj];
    }
    #pragma unroll
    for (int i = 0; i < 2; ++i)
        #pragma unroll
        for (int jj = 0; jj < 4; ++jj)
            acc[i][jj] += bb[jj];

    float sp[2] = {0.f, 0.f}, dp[2] = {0.f, 0.f};
    #pragma unroll
    for (int i = 0; i < 2; ++i)
        #pragma unroll
        for (int jj = 0; jj < 4; ++jj) {
            sp[i] = fmaf(acc[i][jj], as_[jj], sp[i]);
            dp[i] = fmaf(acc[i][jj], ad_[jj], dp[i]);
        }
    #pragma unroll
    for (int off = 1; off < 16; off <<= 1) {
        #pragma unroll
        for (int i = 0; i < 2; ++i) {
            sp[i] += __shfl_xor(sp[i], off);
            dp[i] += __shfl_xor(dp[i], off);
        }
    }
    if (og == 0) {
        #pragma unroll
        for (int i = 0; i < 2; ++i) {
            int nn = n0 + rg * 2 + i;
            s_out[h * NN + nn] = sp[i];
            d_out[h * NN + nn] = dp[i];
        }
    }

    // fp32 row-major copy (finalize reads this for the diagonal term)
    #pragma unroll
    for (int i = 0; i < 2; ++i) {
        float4 v = make_float4(acc[i][0], acc[i][1], acc[i][2], acc[i][3]);
        *(float4*)&Hrow[((size_t)h * NN + n0 + rg * 2 + i) * FOUT + og * 4] = v;
    }
    // bf16 transposed copy (MFMA B-operand; n contiguous)
    #pragma unroll
    for (int jj = 0; jj < 4; ++jj) {
        int o = og * 4 + jj;
        ushort2 p;
        p.x = f32_bf16(acc[0][jj]);
        p.y = f32_bf16(acc[1][jj]);
        *(ushort2*)&HbfT[((size_t)h * FOUT + o) * NN + n0 + rg * 2] = p;
    }
}

// ---------------- Kernel 2: masked softmax-aggregate (K-split partials) ------
// grid (256 row-tiles, 4 K-splits), 512 threads = 8 waves = 4 heads x 2 subchunks.
// Emits unnormalized sum_m w*H into Hacc[h][n][o] and sum_m w into lpart[h][n].
__global__ __launch_bounds__(512, 8) void gat_main(
    const int* __restrict__ A, const unsigned short* __restrict__ HbfT,
    const float* __restrict__ s_g, const float* __restrict__ d_g,
    float* __restrict__ Hacc, float* __restrict__ lpart)
{
    const int n0   = blockIdx.x * 16;
    const int by   = blockIdx.y;         // K split 0..3 -> cols [by*1024, +1024)
    const int tid  = threadIdx.x;
    const int wv   = tid >> 6;           // 0..7
    const int h    = wv & 3;
    const int sub  = wv >> 2;            // sub-chunk of 512 cols
    const int lane = tid & 63;
    const int r    = lane & 15;          // A-operand row / B-operand col
    const int q    = lane >> 4;          // quad -> k offset q*8

    __shared__ float out_acc[4][16][64]; // per-head unnormalized tile, 16 KB
    __shared__ float l_lds[8][16];

    for (int g = tid; g < 4 * 16 * 64; g += 512) ((float*)out_acc)[g] = 0.0f;
    __syncthreads();

    const int n = n0 + r;
    const float s_h = s_g[h * NN + n];
    const float* dh = d_g + h * NN;
    const long  arow = (long)n * NN;
    const unsigned short* hb_base = HbfT + ((size_t)h * FOUT + r) * NN;

    f32x4 acc0 = {0,0,0,0}, acc1 = {0,0,0,0}, acc2 = {0,0,0,0}, acc3 = {0,0,0,0};
    float l_part = 0.f;
    const int m0 = by * 1024 + sub * 512 + q * 8;

    #pragma unroll 2
    for (int step = 0; step < 16; ++step) {
        const int mk = m0 + step * 32;
        const int4   a0  = *(const int4*)  &A[arow + mk];
        const int4   a1  = *(const int4*)  &A[arow + mk + 4];
        const float4 dd0 = *(const float4*)&dh[mk];
        const float4 dd1 = *(const float4*)&dh[mk + 4];

        float dv[8] = {dd0.x, dd0.y, dd0.z, dd0.w, dd1.x, dd1.y, dd1.z, dd1.w};
        int   av[8] = {a0.x, a0.y, a0.z, a0.w, a1.x, a1.y, a1.z, a1.w};

        bf16x8 af;
        float lsum = 0.f;
        #pragma unroll
        for (int j = 0; j < 8; ++j) {
            float tt = s_h + dv[j];
            float lr = fmaxf(tt, 0.01f * tt);   // leaky_relu
            float e  = __expf(lr);
            float w  = (av[j] > 0) ? e : 0.0f;  // diag: A[n][n]==0, added in finalize
            lsum += w;
            af[j] = (short)f32_bf16(w);
        }
        l_part += lsum;

        const unsigned short* hb = hb_base + mk;
        bf16x8 b0 = *(const bf16x8*)(hb);
        bf16x8 b1 = *(const bf16x8*)(hb + 16 * NN);
        bf16x8 b2 = *(const bf16x8*)(hb + 32 * NN);
        bf16x8 b3 = *(const bf16x8*)(hb + 48 * NN);
        acc0 = __builtin_amdgcn_mfma_f32_16x16x32_bf16(af, b0, acc0, 0, 0, 0);
        acc1 = __builtin_amdgcn_mfma_f32_16x16x32_bf16(af, b1, acc1, 0, 0, 0);
        acc2 = __builtin_amdgcn_mfma_f32_16x16x32_bf16(af, b2, acc2, 0, 0, 0);
        acc3 = __builtin_amdgcn_mfma_f32_16x16x32_bf16(af, b3, acc3, 0, 0, 0);
    }

    // denominator partial: reduce across quads, across the 2 sub-waves, then atomic
    l_part += __shfl_xor(l_part, 16);
    l_part += __shfl_xor(l_part, 32);
    if (lane < 16) l_lds[wv][r] = l_part;
    __syncthreads();
    if (wv < 4 && lane < 16)
        atomicAdd(&lpart[h * NN + n0 + lane], l_lds[h][lane] + l_lds[h + 4][lane]);

    // merge the 2 sub-waves per head in LDS (unnormalized)
    #pragma unroll
    for (int reg = 0; reg < 4; ++reg) {
        int rr = q * 4 + reg;
        atomicAdd(&out_acc[h][rr][ 0 + r], acc0[reg]);
        atomicAdd(&out_acc[h][rr][16 + r], acc1[reg]);
        atomicAdd(&out_acc[h][rr][32 + r], acc2[reg]);
        atomicAdd(&out_acc[h][rr][48 + r], acc3[reg]);
    }
    __syncthreads();

    // block -> global partial accumulation (coalesced dword atomics)
    #pragma unroll
    for (int i = 0; i < 8; ++i) {
        int idx = i * 512 + tid;             // 0..4095
        int hh = idx >> 10;
        int rr = (idx >> 6) & 15;
        int oo = idx & 63;
        atomicAdd(&Hacc[((size_t)hh * NN + n0 + rr) * FOUT + oo],
                  out_acc[hh][rr][oo]);
    }
}

// ---------------- Kernel 3: finalize ----------------
// out[n][o] = sum_h (Hacc[h][n][o] + w_diag*Hrow[h][n][o]) * 0.25/(l[h][n]+w_diag)
__global__ __launch_bounds__(256) void gat_fin(
    const float* __restrict__ Hacc, const float* __restrict__ Hrow,
    const float* __restrict__ lpart, const float* __restrict__ s_g,
    const float* __restrict__ d_g, float* __restrict__ out)
{
    const int tid = threadIdx.x;
    const int rr  = tid >> 4;            // 0..15
    const int c4  = tid & 15;            // float4 column group
    const int n   = blockIdx.x * 16 + rr;
    const int o   = c4 * 4;

    float4 res = make_float4(0.f, 0.f, 0.f, 0.f);
    #pragma unroll
    for (int h = 0; h < NH; ++h) {
        float l  = lpart[h * NN + n];
        float tt = s_g[h * NN + n] + d_g[h * NN + n];
        float wd = __expf(fmaxf(tt, 0.01f * tt));   // self-edge weight
        float inv = 0.25f / (l + wd);
        float4 ha = *(const float4*)&Hacc[((size_t)h * NN + n) * FOUT + o];
        float4 hr = *(const float4*)&Hrow[((size_t)h * NN + n) * FOUT + o];
        res.x += (ha.x + wd * hr.x) * inv;
        res.y += (ha.y + wd * hr.y) * inv;
        res.z += (ha.z + wd * hr.z) * inv;
        res.w += (ha.w + wd * hr.w) * inv;
    }
    *(float4*)&out[(size_t)n * FOUT + o] = res;
}

extern "C" void kernel_launch(void* const* d_in, const int* in_sizes, int n_in,
                              void* d_out, int out_size, void* d_ws, size_t ws_size,
                              hipStream_t stream) {
    const float* X   = (const float*)d_in[0];
    const int*   A   = (const int*)  d_in[1];
    const float* W   = (const float*)d_in[2];
    const float* b   = (const float*)d_in[3];
    const float* att = (const float*)d_in[4];
    float* out = (float*)d_out;

    char* ws = (char*)d_ws;
    unsigned short* HbfT = (unsigned short*)ws;                    // 2 MB
    size_t off = (size_t)NH * FOUT * NN * 2;
    float* s_buf = (float*)(ws + off);  off += (size_t)NH * NN * 4;   // 64 KB
    float* d_buf = (float*)(ws + off);  off += (size_t)NH * NN * 4;   // 64 KB
    float* Hacc  = (float*)(ws + off);  off += (size_t)NH * NN * FOUT * 4; // 4 MB
    float* lpart = (float*)(ws + off);  off += (size_t)NH * NN * 4;   // 64 KB
    float* Hrow  = (float*)(ws + off);  off += (size_t)NH * NN * FOUT * 4; // 4 MB

    // zero Hacc + lpart (contiguous): (4*4096*64 + 4*4096) floats / 4 per float4
    const int n4 = (NH * NN * FOUT + NH * NN) / 4;                 // 266240
    zero_f4<<<(n4 + 255) / 256, 256, 0, stream>>>((float4*)Hacc, n4);
    gat_prep<<<dim3(128, 4), 256, 0, stream>>>(X, W, b, att, HbfT, Hrow, s_buf, d_buf);
    gat_main<<<dim3(256, 4), 512, 0, stream>>>(A, HbfT, s_buf, d_buf, Hacc, lpart);
    gat_fin<<<256, 256, 0, stream>>>(Hacc, Hrow, lpart, s_buf, d_buf, out);
}